// Round 9
// baseline (78.259 us; speedup 1.0000x reference)
//
#include <hip/hip_runtime.h>

// Signature-kernel MMD, fused. R9 = R8 (verified) + ONE delta: Gram-phase
// broadcast via v_readlane (row u is loop-uniform) instead of LDS xs/xxs
// reads -> zero DS traffic in the Gram loop (was 128 reads/wave incl. 64
// ds_read_b128). binc layout/writes and PDE loop are byte-identical to R8.
// E-stream via DPP identity eF(k) = wave_shr1(oF(k-1)) (verified R7/R8).
// 768 blocks x 256 thr (4 waves/block, 3 blocks/CU), fp16 row-major binc
// stride 66 zero-padded; out-of-window reads return 0 and/or are multiplied
// by exactly-zero state (verified R2/R3/R4/R6).

constexpr int S2  = 66;     // binc row stride (fp16 elems)
constexpr int PAD = 64;     // front pad (covers negative column offsets)
constexpr int BNA = 4368;   // per-pair buffer (PAD + 63*66 + rear pad, 16B-mult)

__global__ void zero_kernel(float* out) { out[0] = 0.0f; }

__device__ __forceinline__ float dpp_shr1(float v) {
    // result[l] = src[l-1], result[0] = 0
    return __builtin_bit_cast(float,
        __builtin_amdgcn_update_dpp(0, __builtin_bit_cast(int, v), 0x138, 0xF, 0xF, true));
}
__device__ __forceinline__ float dpp_shl1(float v) {
    // result[l] = src[l+1], result[63] = 0
    return __builtin_bit_cast(float,
        __builtin_amdgcn_update_dpp(0, __builtin_bit_cast(int, v), 0x130, 0xF, 0xF, true));
}
__device__ __forceinline__ float rdlane(float v, int l) {
    // uniform-lane broadcast, VALU pipe (no LDS)
    return __builtin_bit_cast(float,
        __builtin_amdgcn_readlane(__builtin_bit_cast(int, v), l));
}
__device__ __forceinline__ float dot4(float4 a, float4 b) {
    return a.x * b.x + a.y * b.y + a.z * b.z + a.w * b.w;
}

// Two PDE substeps (antidiagonals 2k-1, 2k); ef/of are RAW binc values.
// State: p1E,p1O (diag d-1), p2E (E diag d-2), up2 (shr1 of O diag d-2),
// oP (previous body's of). Verified R3/R6.
#define BODY(ef, of) {                                 \
    float up1 = dpp_shr1(p1O);                         \
    float cE  = (up1 - up2) + p1E + up2 * (ef);        \
    float cO  = (p1E - p2E) + p1O + p2E * oP;          \
    float nu2 = up1, np2 = p1E;                        \
    p1E = cE; p1O = cO;                                \
    up1 = dpp_shr1(p1O);                               \
    cE  = (up1 - nu2) + p1E + nu2 * (ef);              \
    cO  = (p1E - np2) + p1O + np2 * (of);              \
    up2 = up1; p2E = p1E; p1E = cE; p1O = cO;          \
    oP  = (of); }

// Body with E derived from previous body's O float via DPP (verified R7/R8).
#define EBODY(foCur) {                                 \
    float eF = dpp_shr1(foPrev);                       \
    BODY(eF, foCur)                                    \
    foPrev = (foCur); }

__global__ __launch_bounds__(256) void sigpde_kernel(const float* __restrict__ x,
                                                     const float* __restrict__ y,
                                                     float* __restrict__ out) {
    __shared__ __align__(16) _Float16 binc[4][BNA];   // 34944 B
    __shared__ float  partial[4];

    const int lane = threadIdx.x & 63;
    const int wid  = threadIdx.x >> 6;
    const int p = blockIdx.x * 4 + wid;     // 0..3071
    const int g = p >> 10;                  // 0: xx, 1: xy, 2: yy
    const int q = p & 1023;
    const int a = q >> 5, b = q & 31;
    const float* Ab = (g == 2) ? y : x;
    const float* Bb = (g == 0) ? x : y;

    _Float16* bw = &binc[wid][0];

    float4 xa = ((const float4*)(Ab + a * 256))[lane];
    float4 yv = ((const float4*)(Bb + b * 256))[lane];
    const float xx = dot4(xa, xa);
    const float yy = dot4(yv, yv);

    {   // zero this wave's buffer (pads/gaps must be finite zeros)
        uint4* z = (uint4*)bw;
        const uint4 zz = {0u, 0u, 0u, 0u};
        for (int i = lane; i < BNA / 8; i += 64) z[i] = zz;
    }
    // No barrier: all LDS below is wave-private; same-wave ds ordering
    // is guaranteed via lgkmcnt.

    // Gram + double increments (column = lane). Row-u broadcast via
    // v_readlane (u uniform) -> pure VALU, zero DS traffic:
    // binc[u-1][lane] = 0.25*((G[u][l+1]-G[u][l]) - (G[u-1][l+1]-G[u-1][l]))
    float dp = 0.0f;
    #pragma unroll 4
    for (int u = 0; u < 64; ++u) {
        float x0 = rdlane(xa.x, u), x1 = rdlane(xa.y, u);
        float x2 = rdlane(xa.z, u), x3 = rdlane(xa.w, u);
        float xxu = rdlane(xx, u);
        float dot = x0 * yv.x + x1 * yv.y + x2 * yv.z + x3 * yv.w;
        float t = xxu + yy - 2.0f * dot;
        float gv = __expf(-0.5f * t);
        float d = dpp_shl1(gv) - gv;
        if (u > 0) bw[PAD + (u - 1) * S2 + lane] = (_Float16)(0.25f * (d - dp));
        dp = d;
    }

    // Goursat PDE: lane owns rows iE=2l, iO=2l+1; body k = diagonals 2k-1,2k.
    // Single O-stream: body k loads oA[k-1] = binc[l][k-1-l]; the E factor is
    // eF(k) = shr1(oF(k-1)) (lane l-1's O value of the previous body).
    const int rO = (lane <= 62) ? lane : 62;
    const _Float16* oA = bw + PAD + rO * S2 - lane;

    float p1E = (lane == 0) ? 1.0f : 0.0f;  // diag 0 seed: K[0,0]=1
    float p1O = 0.0f, p2E = 0.0f, up2 = 0.0f, oP = 0.0f;
    float foPrev = 0.0f;                    // oF(0): out-of-window -> 0

    // warmup: bodies 1,2 converted; bodies 3,4 in flight (R6 structure)
    _Float16 ho2 = oA[2], ho3 = oA[3];
    float fo0 = (float)oA[0], fo1 = (float)oA[1];

    #pragma unroll 2
    for (int k = 1; k <= 125; k += 2) {
        // convert bodies k+2, k+3 (loaded last iteration)  [R6 order]
        float go2 = (float)ho2, go3 = (float)ho3;
        // prefetch bodies k+4, k+5
        ho2 = oA[k + 3]; ho3 = oA[k + 4];
        // compute bodies k, k+1
        EBODY(fo0)
        EBODY(fo1)
        // rotate pipeline
        fo0 = go2; fo1 = go3;
    }

    // K[126,126] = lane 63's E slot after diagonal 252.
    if (lane == 63) {
        float w = (g == 1) ? (-2.0f / 1024.0f) : (1.0f / 1024.0f);
        partial[wid] = w * p1E;
    }
    __syncthreads();
    if (threadIdx.x == 0) {
        atomicAdd(out, (partial[0] + partial[1]) + (partial[2] + partial[3]));
    }
}

extern "C" void kernel_launch(void* const* d_in, const int* in_sizes, int n_in,
                              void* d_out, int out_size, void* d_ws, size_t ws_size,
                              hipStream_t stream) {
    const float* x = (const float*)d_in[0];
    const float* y = (const float*)d_in[1];
    float* out = (float*)d_out;
    (void)in_sizes; (void)n_in; (void)out_size; (void)d_ws; (void)ws_size;

    hipLaunchKernelGGL(zero_kernel, dim3(1), dim3(1), 0, stream, out);
    hipLaunchKernelGGL(sigpde_kernel, dim3(768), dim3(256), 0, stream, x, y, out);
}

// Round 10
// 77.980 us; speedup vs baseline: 1.0036x; 1.0036x over previous
//
#include <hip/hip_runtime.h>

// Signature-kernel MMD, fused. R10 = R8 (verified base) + ONE delta: PDE
// software pipeline depth 4 -> 8 bodies, manual 4-body loop, convert-THEN-
// prefetch order. Converts consume loads issued one full asm-iteration
// (~140+ issue cycles) earlier, so even a conservative lgkmcnt(0) wait is
// nearly free. (R7's regression used loads-first order, which forces a
// full-latency drain of just-issued loads each iteration.)
// Everything else identical to R8: 768 blocks x 256 thr (4 waves/block,
// 3 blocks/CU), LDS-based Gram, fp16 row-major binc stride 66 zero-padded,
// E-stream via DPP identity eF(k) = wave_shr1(oF(k-1)) (verified R7/R8).
// Out-of-window reads return 0 and/or are multiplied by exactly-zero state
// (verified R2/R3/R4/R6).

constexpr int S2  = 66;     // binc row stride (fp16 elems)
constexpr int PAD = 64;     // front pad (covers negative column offsets)
constexpr int BNA = 4368;   // per-pair buffer (PAD + 63*66 + rear pad, 16B-mult)

__global__ void zero_kernel(float* out) { out[0] = 0.0f; }

__device__ __forceinline__ float dpp_shr1(float v) {
    // result[l] = src[l-1], result[0] = 0
    return __builtin_bit_cast(float,
        __builtin_amdgcn_update_dpp(0, __builtin_bit_cast(int, v), 0x138, 0xF, 0xF, true));
}
__device__ __forceinline__ float dpp_shl1(float v) {
    // result[l] = src[l+1], result[63] = 0
    return __builtin_bit_cast(float,
        __builtin_amdgcn_update_dpp(0, __builtin_bit_cast(int, v), 0x130, 0xF, 0xF, true));
}
__device__ __forceinline__ float dot4(float4 a, float4 b) {
    return a.x * b.x + a.y * b.y + a.z * b.z + a.w * b.w;
}

// Two PDE substeps (antidiagonals 2k-1, 2k); ef/of are RAW binc values.
// State: p1E,p1O (diag d-1), p2E (E diag d-2), up2 (shr1 of O diag d-2),
// oP (previous body's of). Verified R3/R6.
#define BODY(ef, of) {                                 \
    float up1 = dpp_shr1(p1O);                         \
    float cE  = (up1 - up2) + p1E + up2 * (ef);        \
    float cO  = (p1E - p2E) + p1O + p2E * oP;          \
    float nu2 = up1, np2 = p1E;                        \
    p1E = cE; p1O = cO;                                \
    up1 = dpp_shr1(p1O);                               \
    cE  = (up1 - nu2) + p1E + nu2 * (ef);              \
    cO  = (p1E - np2) + p1O + np2 * (of);              \
    up2 = up1; p2E = p1E; p1E = cE; p1O = cO;          \
    oP  = (of); }

// Body with E derived from previous body's O float via DPP (verified R7/R8).
#define EBODY(foCur) {                                 \
    float eF = dpp_shr1(foPrev);                       \
    BODY(eF, foCur)                                    \
    foPrev = (foCur); }

__global__ __launch_bounds__(256) void sigpde_kernel(const float* __restrict__ x,
                                                     const float* __restrict__ y,
                                                     float* __restrict__ out) {
    __shared__ __align__(16) _Float16 binc[4][BNA];   // 34944 B
    __shared__ float4 xs[4][64];                      //  4096 B
    __shared__ float  xxs[4][64];                     //  1024 B
    __shared__ float  partial[4];

    const int lane = threadIdx.x & 63;
    const int wid  = threadIdx.x >> 6;
    const int p = blockIdx.x * 4 + wid;     // 0..3071
    const int g = p >> 10;                  // 0: xx, 1: xy, 2: yy
    const int q = p & 1023;
    const int a = q >> 5, b = q & 31;
    const float* Ab = (g == 2) ? y : x;
    const float* Bb = (g == 0) ? x : y;

    _Float16* bw = &binc[wid][0];

    float4 xa = ((const float4*)(Ab + a * 256))[lane];
    float4 yv = ((const float4*)(Bb + b * 256))[lane];
    xs[wid][lane]  = xa;
    xxs[wid][lane] = dot4(xa, xa);
    const float yy = dot4(yv, yv);

    {   // zero this wave's buffer (pads/gaps must be finite zeros)
        uint4* z = (uint4*)bw;
        const uint4 zz = {0u, 0u, 0u, 0u};
        for (int i = lane; i < BNA / 8; i += 64) z[i] = zz;
    }
    // No barrier: all LDS below is wave-private; same-wave ds ordering
    // is guaranteed via lgkmcnt.

    // Gram + double increments (column = lane), verified R6:
    // binc[u-1][lane] = 0.25*((G[u][l+1]-G[u][l]) - (G[u-1][l+1]-G[u-1][l]))
    float dp = 0.0f;
    #pragma unroll 4
    for (int u = 0; u < 64; ++u) {
        float4 xu = xs[wid][u];            // broadcast read
        float t = xxs[wid][u] + yy - 2.0f * dot4(xu, yv);
        float gv = __expf(-0.5f * t);
        float d = dpp_shl1(gv) - gv;
        if (u > 0) bw[PAD + (u - 1) * S2 + lane] = (_Float16)(0.25f * (d - dp));
        dp = d;
    }

    // Goursat PDE: lane owns rows iE=2l, iO=2l+1; body k = diagonals 2k-1,2k.
    // Single O-stream: body k loads oA[k-1] = binc[l][k-1-l]; the E factor is
    // eF(k) = shr1(oF(k-1)) (lane l-1's O value of the previous body).
    const int rO = (lane <= 62) ? lane : 62;
    const _Float16* oA = bw + PAD + rO * S2 - lane;

    float p1E = (lane == 0) ? 1.0f : 0.0f;  // diag 0 seed: K[0,0]=1
    float p1O = 0.0f, p2E = 0.0f, up2 = 0.0f, oP = 0.0f;
    float foPrev = 0.0f;                    // oF(0): out-of-window -> 0

    // Depth-8 pipeline: fo0..fo3 = bodies 1..4 (converted);
    // h0..h3 = bodies 5..8 (raw, in flight).
    float fo0 = (float)oA[0], fo1 = (float)oA[1];
    float fo2 = (float)oA[2], fo3 = (float)oA[3];
    _Float16 h0 = oA[4], h1 = oA[5], h2 = oA[6], h3 = oA[7];

    for (int i = 0; i < 31; ++i) {          // bodies B..B+3, B = 1+4i (1..124)
        // convert bodies B+4..B+7 (loads issued one full iteration ago)
        float g0 = (float)h0, g1 = (float)h1, g2 = (float)h2, g3 = (float)h3;
        // prefetch bodies B+8..B+11  (max index 131 < 4368-offset: in-bounds)
        h0 = oA[4 * i + 8]; h1 = oA[4 * i + 9];
        h2 = oA[4 * i + 10]; h3 = oA[4 * i + 11];
        // compute bodies B..B+3
        EBODY(fo0) EBODY(fo1) EBODY(fo2) EBODY(fo3)
        // rotate pipeline
        fo0 = g0; fo1 = g1; fo2 = g2; fo3 = g3;
    }
    // tail: bodies 125, 126 (fo0, fo1)
    EBODY(fo0) EBODY(fo1)

    // K[126,126] = lane 63's E slot after diagonal 252.
    if (lane == 63) {
        float w = (g == 1) ? (-2.0f / 1024.0f) : (1.0f / 1024.0f);
        partial[wid] = w * p1E;
    }
    __syncthreads();
    if (threadIdx.x == 0) {
        atomicAdd(out, (partial[0] + partial[1]) + (partial[2] + partial[3]));
    }
}

extern "C" void kernel_launch(void* const* d_in, const int* in_sizes, int n_in,
                              void* d_out, int out_size, void* d_ws, size_t ws_size,
                              hipStream_t stream) {
    const float* x = (const float*)d_in[0];
    const float* y = (const float*)d_in[1];
    float* out = (float*)d_out;
    (void)in_sizes; (void)n_in; (void)out_size; (void)d_ws; (void)ws_size;

    hipLaunchKernelGGL(zero_kernel, dim3(1), dim3(1), 0, stream, out);
    hipLaunchKernelGGL(sigpde_kernel, dim3(768), dim3(256), 0, stream, x, y, out);
}

// Round 11
// 74.478 us; speedup vs baseline: 1.0508x; 1.0470x over previous
//
#include <hip/hip_runtime.h>

// Signature-kernel MMD, fused. R11 = R8 (verified base) + ONE delta: the
// epilogue atomic funnel (768 same-address device-scope atomicAdds, issued
// nearly simultaneously by uniformly-loaded blocks -> serialized L2 tail) is
// replaced by per-wave partial stores to d_ws + a tiny reduce kernel that
// writes out[0] (replaces zero_kernel; dispatch count unchanged at 2).
// Everything else identical to R8: 768 blocks x 256 thr (4 waves/block,
// 3 blocks/CU), LDS Gram with broadcast reads, fp16 row-major binc stride 66
// zero-padded, E-stream via DPP identity eF(k)=wave_shr1(oF(k-1)) (verified
// R7/R8). Out-of-window reads return 0 and/or are multiplied by exactly-zero
// state (verified R2/R3/R4/R6).

constexpr int S2  = 66;     // binc row stride (fp16 elems)
constexpr int PAD = 64;     // front pad (covers negative column offsets)
constexpr int BNA = 4368;   // per-pair buffer (PAD + 63*66 + rear pad, 16B-mult)

__device__ __forceinline__ float dpp_shr1(float v) {
    // result[l] = src[l-1], result[0] = 0
    return __builtin_bit_cast(float,
        __builtin_amdgcn_update_dpp(0, __builtin_bit_cast(int, v), 0x138, 0xF, 0xF, true));
}
__device__ __forceinline__ float dpp_shl1(float v) {
    // result[l] = src[l+1], result[63] = 0
    return __builtin_bit_cast(float,
        __builtin_amdgcn_update_dpp(0, __builtin_bit_cast(int, v), 0x130, 0xF, 0xF, true));
}
__device__ __forceinline__ float dot4(float4 a, float4 b) {
    return a.x * b.x + a.y * b.y + a.z * b.z + a.w * b.w;
}

// Two PDE substeps (antidiagonals 2k-1, 2k); ef/of are RAW binc values.
// State: p1E,p1O (diag d-1), p2E (E diag d-2), up2 (shr1 of O diag d-2),
// oP (previous body's of). Verified R3/R6.
#define BODY(ef, of) {                                 \
    float up1 = dpp_shr1(p1O);                         \
    float cE  = (up1 - up2) + p1E + up2 * (ef);        \
    float cO  = (p1E - p2E) + p1O + p2E * oP;          \
    float nu2 = up1, np2 = p1E;                        \
    p1E = cE; p1O = cO;                                \
    up1 = dpp_shr1(p1O);                               \
    cE  = (up1 - nu2) + p1E + nu2 * (ef);              \
    cO  = (p1E - np2) + p1O + np2 * (of);              \
    up2 = up1; p2E = p1E; p1E = cE; p1O = cO;          \
    oP  = (of); }

// Body with E derived from previous body's O float via DPP (verified R7/R8).
#define EBODY(foCur) {                                 \
    float eF = dpp_shr1(foPrev);                       \
    BODY(eF, foCur)                                    \
    foPrev = (foCur); }

__global__ __launch_bounds__(256) void sigpde_kernel(const float* __restrict__ x,
                                                     const float* __restrict__ y,
                                                     float* __restrict__ pws) {
    __shared__ __align__(16) _Float16 binc[4][BNA];   // 34944 B
    __shared__ float4 xs[4][64];                      //  4096 B
    __shared__ float  xxs[4][64];                     //  1024 B

    const int lane = threadIdx.x & 63;
    const int wid  = threadIdx.x >> 6;
    const int p = blockIdx.x * 4 + wid;     // 0..3071
    const int g = p >> 10;                  // 0: xx, 1: xy, 2: yy
    const int q = p & 1023;
    const int a = q >> 5, b = q & 31;
    const float* Ab = (g == 2) ? y : x;
    const float* Bb = (g == 0) ? x : y;

    _Float16* bw = &binc[wid][0];

    float4 xa = ((const float4*)(Ab + a * 256))[lane];
    float4 yv = ((const float4*)(Bb + b * 256))[lane];
    xs[wid][lane]  = xa;
    xxs[wid][lane] = dot4(xa, xa);
    const float yy = dot4(yv, yv);

    {   // zero this wave's buffer (pads/gaps must be finite zeros)
        uint4* z = (uint4*)bw;
        const uint4 zz = {0u, 0u, 0u, 0u};
        for (int i = lane; i < BNA / 8; i += 64) z[i] = zz;
    }
    // No barrier anywhere: all LDS is wave-private; same-wave ds ordering
    // is guaranteed via lgkmcnt.

    // Gram + double increments (column = lane), verified R6:
    // binc[u-1][lane] = 0.25*((G[u][l+1]-G[u][l]) - (G[u-1][l+1]-G[u-1][l]))
    float dp = 0.0f;
    #pragma unroll 4
    for (int u = 0; u < 64; ++u) {
        float4 xu = xs[wid][u];            // broadcast read
        float t = xxs[wid][u] + yy - 2.0f * dot4(xu, yv);
        float gv = __expf(-0.5f * t);
        float d = dpp_shl1(gv) - gv;
        if (u > 0) bw[PAD + (u - 1) * S2 + lane] = (_Float16)(0.25f * (d - dp));
        dp = d;
    }

    // Goursat PDE: lane owns rows iE=2l, iO=2l+1; body k = diagonals 2k-1,2k.
    // Single O-stream: body k loads oA[k-1] = binc[l][k-1-l]; the E factor is
    // eF(k) = shr1(oF(k-1)) (lane l-1's O value of the previous body).
    const int rO = (lane <= 62) ? lane : 62;
    const _Float16* oA = bw + PAD + rO * S2 - lane;

    float p1E = (lane == 0) ? 1.0f : 0.0f;  // diag 0 seed: K[0,0]=1
    float p1O = 0.0f, p2E = 0.0f, up2 = 0.0f, oP = 0.0f;
    float foPrev = 0.0f;                    // oF(0): out-of-window -> 0

    // warmup: bodies 1,2 converted; bodies 3,4 in flight (R6 structure)
    _Float16 ho2 = oA[2], ho3 = oA[3];
    float fo0 = (float)oA[0], fo1 = (float)oA[1];

    #pragma unroll 2
    for (int k = 1; k <= 125; k += 2) {
        // convert bodies k+2, k+3 (loaded last iteration)  [R6 order]
        float go2 = (float)ho2, go3 = (float)ho3;
        // prefetch bodies k+4, k+5
        ho2 = oA[k + 3]; ho3 = oA[k + 4];
        // compute bodies k, k+1
        EBODY(fo0)
        EBODY(fo1)
        // rotate pipeline
        fo0 = go2; fo1 = go3;
    }

    // K[126,126] = lane 63's E slot after diagonal 252. Plain store, no atomic.
    if (lane == 63) {
        float w = (g == 1) ? (-2.0f / 1024.0f) : (1.0f / 1024.0f);
        pws[p] = w * p1E;
    }
}

__global__ __launch_bounds__(256) void reduce_kernel(const float* __restrict__ pws,
                                                     float* __restrict__ out) {
    // Sum 3072 weighted partials (768 float4 loads), write out[0].
    float s = 0.0f;
    const float4* v = (const float4*)pws;
    for (int i = threadIdx.x; i < 768; i += 256) {
        float4 t = v[i];
        s += (t.x + t.y) + (t.z + t.w);
    }
    for (int off = 32; off > 0; off >>= 1) s += __shfl_down(s, off);
    __shared__ float ws[4];
    if ((threadIdx.x & 63) == 0) ws[threadIdx.x >> 6] = s;
    __syncthreads();
    if (threadIdx.x == 0) out[0] = (ws[0] + ws[1]) + (ws[2] + ws[3]);
}

extern "C" void kernel_launch(void* const* d_in, const int* in_sizes, int n_in,
                              void* d_out, int out_size, void* d_ws, size_t ws_size,
                              hipStream_t stream) {
    const float* x = (const float*)d_in[0];
    const float* y = (const float*)d_in[1];
    float* out = (float*)d_out;
    float* pws = (float*)d_ws;    // 3072 floats = 12 KB << ws_size
    (void)in_sizes; (void)n_in; (void)out_size; (void)ws_size;

    hipLaunchKernelGGL(sigpde_kernel, dim3(768), dim3(256), 0, stream, x, y, pws);
    hipLaunchKernelGGL(reduce_kernel, dim3(1), dim3(256), 0, stream, pws, out);
}